// Round 2
// baseline (147.294 us; speedup 1.0000x reference)
//
#include <hip/hip_runtime.h>
#include <hip/hip_bf16.h>

// GraphAttentionLayer fused kernel for MI355X (gfx950).
// N=8192, IN=512, OUT=64. adj read (256MB) is the HBM floor (~43us).
// K-A: Wh = h@W (fp32), Wh1/Wh2 rank-1 score vectors, WhbT bf16 [64][8192].
// K-B: flash-style fused mask+softmax+PV with mfma_f32_16x16x32_bf16.
// Output is fp32 (reference output dtype).

#define NEG_BIG (-9e15f)

typedef __attribute__((ext_vector_type(8))) short  short8v;
typedef __attribute__((ext_vector_type(8))) unsigned short ushort8v;
typedef __attribute__((ext_vector_type(4))) float  f32x4;

__device__ __forceinline__ unsigned short f2bf(float f) {
    union { float f; unsigned int u; } x; x.f = f;
    unsigned int r = x.u + 0x7FFFu + ((x.u >> 16) & 1u);   // RNE
    return (unsigned short)(r >> 16);
}

// ---------------- Kernel A: Wh, Wh1, Wh2, WhbT ----------------
// grid 256 x 256 threads. wave handles 8 rows; lane = output col.
__global__ __launch_bounds__(256) void wh_kernel(
        const float* __restrict__ h, const float* __restrict__ W,
        const float* __restrict__ a,
        unsigned short* __restrict__ WhbT,
        float* __restrict__ Wh1, float* __restrict__ Wh2) {
    const int wave = threadIdx.x >> 6;
    const int lane = threadIdx.x & 63;
    const int row0 = (blockIdx.x * 4 + wave) * 8;

    float acc[8];
#pragma unroll
    for (int rr = 0; rr < 8; ++rr) acc[rr] = 0.f;

    const float* hrow = h + (size_t)row0 * 512;
    for (int i = 0; i < 512; i += 4) {
        float w0 = W[(i + 0) * 64 + lane];
        float w1 = W[(i + 1) * 64 + lane];
        float w2 = W[(i + 2) * 64 + lane];
        float w3 = W[(i + 3) * 64 + lane];
#pragma unroll
        for (int rr = 0; rr < 8; ++rr) {
            float4 hv = *reinterpret_cast<const float4*>(hrow + (size_t)rr * 512 + i);
            acc[rr] = fmaf(hv.x, w0, fmaf(hv.y, w1, fmaf(hv.z, w2, fmaf(hv.w, w3, acc[rr]))));
        }
    }

    // WhbT[col][row] bf16, 16B store per lane
    ushort8v bt;
#pragma unroll
    for (int rr = 0; rr < 8; ++rr) bt[rr] = f2bf(acc[rr]);
    *reinterpret_cast<ushort8v*>(WhbT + (size_t)lane * 8192 + row0) = bt;

    // rank-1 score vectors
    float a1 = a[lane], a2 = a[lane + 64];
#pragma unroll
    for (int rr = 0; rr < 8; ++rr) {
        float t1 = acc[rr] * a1;
        float t2 = acc[rr] * a2;
#pragma unroll
        for (int off = 32; off; off >>= 1) {
            t1 += __shfl_xor(t1, off);
            t2 += __shfl_xor(t2, off);
        }
        if (lane == 0) { Wh1[row0 + rr] = t1; Wh2[row0 + rr] = t2; }
    }
}

// ---------------- Kernel B: fused mask + softmax + PV ----------------
// grid 512 x 256 threads (4 waves). Block owns 16 rows; waves split j-range.
__global__ __launch_bounds__(256) void attn_kernel(
        const int* __restrict__ adj,
        const unsigned short* __restrict__ WhbT,
        const float* __restrict__ Wh1, const float* __restrict__ Wh2,
        float* __restrict__ out) {
    __shared__ float sm_m[4][16];
    __shared__ float sm_l[4][16];
    __shared__ float sm_acc[4][64][16];

    const int w    = threadIdx.x >> 6;
    const int lane = threadIdx.x & 63;
    const int r    = lane & 15;       // A-frag row / C col
    const int cg   = lane >> 4;       // k-chunk group
    const int i0   = blockIdx.x * 16;
    const int row  = i0 + r;

    const float wh1 = Wh1[row];

    f32x4 acc[4];
#pragma unroll
    for (int f = 0; f < 4; ++f) acc[f] = (f32x4){0.f, 0.f, 0.f, 0.f};
    float m = NEG_BIG;
    float lsum = 0.f;

    const size_t adj_base = (size_t)row * 8192;

    for (int jt = w; jt < 256; jt += 4) {
        const int j0 = jt * 32;
        const int jb = j0 + cg * 8;

        int4 ad0 = *reinterpret_cast<const int4*>(adj + adj_base + jb);
        int4 ad1 = *reinterpret_cast<const int4*>(adj + adj_base + jb + 4);
        float4 w20 = *reinterpret_cast<const float4*>(Wh2 + jb);
        float4 w21 = *reinterpret_cast<const float4*>(Wh2 + jb + 4);

        short8v bf[4];
#pragma unroll
        for (int f = 0; f < 4; ++f)
            bf[f] = *reinterpret_cast<const short8v*>(
                WhbT + (size_t)(16 * f + r) * 8192 + jb);

        float vv[8];
        {
            float t;
            t = wh1 + w20.x; t = t > 0.f ? t : 0.2f * t; vv[0] = ad0.x > 0 ? t : NEG_BIG;
            t = wh1 + w20.y; t = t > 0.f ? t : 0.2f * t; vv[1] = ad0.y > 0 ? t : NEG_BIG;
            t = wh1 + w20.z; t = t > 0.f ? t : 0.2f * t; vv[2] = ad0.z > 0 ? t : NEG_BIG;
            t = wh1 + w20.w; t = t > 0.f ? t : 0.2f * t; vv[3] = ad0.w > 0 ? t : NEG_BIG;
            t = wh1 + w21.x; t = t > 0.f ? t : 0.2f * t; vv[4] = ad1.x > 0 ? t : NEG_BIG;
            t = wh1 + w21.y; t = t > 0.f ? t : 0.2f * t; vv[5] = ad1.y > 0 ? t : NEG_BIG;
            t = wh1 + w21.z; t = t > 0.f ? t : 0.2f * t; vv[6] = ad1.z > 0 ? t : NEG_BIG;
            t = wh1 + w21.w; t = t > 0.f ? t : 0.2f * t; vv[7] = ad1.w > 0 ? t : NEG_BIG;
        }

        float tmax = fmaxf(fmaxf(fmaxf(vv[0], vv[1]), fmaxf(vv[2], vv[3])),
                           fmaxf(fmaxf(vv[4], vv[5]), fmaxf(vv[6], vv[7])));
        tmax = fmaxf(tmax, __shfl_xor(tmax, 16));
        tmax = fmaxf(tmax, __shfl_xor(tmax, 32));

        const float mnew  = fmaxf(m, tmax);
        const float scale = __expf(m - mnew);  // 1.0 when unchanged
        m = mnew;

        float p[8];
        float psum = 0.f;
#pragma unroll
        for (int b = 0; b < 8; ++b) { p[b] = __expf(vv[b] - m); psum += p[b]; }
        lsum = lsum * scale + psum;

        // rescale accumulator: C rows are 4*cg+reg, scale lives on lane==row
        float s0 = __shfl(scale, 4 * cg + 0);
        float s1 = __shfl(scale, 4 * cg + 1);
        float s2 = __shfl(scale, 4 * cg + 2);
        float s3 = __shfl(scale, 4 * cg + 3);
#pragma unroll
        for (int f = 0; f < 4; ++f) {
            acc[f][0] *= s0; acc[f][1] *= s1; acc[f][2] *= s2; acc[f][3] *= s3;
        }

        short8v af;
#pragma unroll
        for (int b = 0; b < 8; ++b) af[b] = (short)f2bf(p[b]);

#pragma unroll
        for (int f = 0; f < 4; ++f)
            acc[f] = __builtin_amdgcn_mfma_f32_16x16x32_bf16(af, bf[f], acc[f], 0, 0, 0);
    }

    // per-row partial sum across the 4 lanes holding row r
    float ls = lsum;
    ls += __shfl_xor(ls, 16);
    ls += __shfl_xor(ls, 32);
    if (lane < 16) { sm_m[w][lane] = m; sm_l[w][lane] = ls; }
    __syncthreads();

    float fac[4];
#pragma unroll
    for (int reg = 0; reg < 4; ++reg) {
        const int R = 4 * cg + reg;
        float m0 = sm_m[0][R], m1 = sm_m[1][R], m2 = sm_m[2][R], m3 = sm_m[3][R];
        float M = fmaxf(fmaxf(m0, m1), fmaxf(m2, m3));
        float L = sm_l[0][R] * __expf(m0 - M) + sm_l[1][R] * __expf(m1 - M)
                + sm_l[2][R] * __expf(m2 - M) + sm_l[3][R] * __expf(m3 - M);
        fac[reg] = __expf(sm_m[w][R] - M) / L;
    }
#pragma unroll
    for (int f = 0; f < 4; ++f)
#pragma unroll
        for (int reg = 0; reg < 4; ++reg)
            sm_acc[w][lane][f * 4 + reg] = acc[f][reg] * fac[reg];
    __syncthreads();

    // wave w finalizes fragment f == w; output fp32
#pragma unroll
    for (int reg = 0; reg < 4; ++reg) {
        float s = sm_acc[0][lane][w * 4 + reg] + sm_acc[1][lane][w * 4 + reg]
                + sm_acc[2][lane][w * 4 + reg] + sm_acc[3][lane][w * 4 + reg];
        float y = s > 0.f ? s : expm1f(s);   // ELU, alpha=1
        const int R = 4 * cg + reg;
        out[(size_t)(i0 + R) * 64 + w * 16 + r] = y;
    }
}

extern "C" void kernel_launch(void* const* d_in, const int* in_sizes, int n_in,
                              void* d_out, int out_size, void* d_ws, size_t ws_size,
                              hipStream_t stream) {
    const float* h   = (const float*)d_in[0];
    const int*   adj = (const int*)d_in[1];
    const float* W   = (const float*)d_in[2];
    const float* a   = (const float*)d_in[3];

    unsigned short* WhbT = (unsigned short*)d_ws;                       // 64*8192*2 = 1MB
    float* Wh1 = (float*)((char*)d_ws + (1 << 20));                     // 32KB
    float* Wh2 = Wh1 + 8192;                                            // 32KB

    wh_kernel<<<256, 256, 0, stream>>>(h, W, a, WhbT, Wh1, Wh2);
    attn_kernel<<<512, 256, 0, stream>>>(adj, WhbT, Wh1, Wh2, (float*)d_out);
}